// Round 7
// baseline (1130.004 us; speedup 1.0000x reference)
//
#include <hip/hip_runtime.h>
#include <math.h>

#define B_ROWS 4096
#define NSTR 4
#define C_DIM 4096
#define NC 16384      // NSTR*C_DIM
#define NC4 4096      // NC/4 (float4 per batch row)
#define C4 1024       // C_DIM/4 (float4 per stream)

// ---------------------------------------------------------------------------
// Kernel 0: repack phi into one contiguous [24][16384] buffer.
// Natural row order: [pre0..3, post0..3, res0..15]
// ---------------------------------------------------------------------------
__global__ void repack_kernel(
    const float4* __restrict__ pre4,
    const float4* __restrict__ post4,
    const float4* __restrict__ res4,
    float4* __restrict__ phiws4)
{
    const int idx = blockIdx.x * blockDim.x + threadIdx.x;   // 0 .. 24*4096-1
    if (idx >= 24 * NC4) return;
    const int row = idx / NC4;
    const int k4  = idx % NC4;
    float4 v;
    if (row < 4)        v = pre4[row * NC4 + k4];
    else if (row < 8)   v = post4[(row - 4) * NC4 + k4];
    else                v = res4[(row - 8) * NC4 + k4];
    phiws4[idx] = v;
}

// ---------------------------------------------------------------------------
// Kernel 1: projections. Grid = (B_ROWS/4) x 2 K-halves -> 2048 blocks.
// Block = 4 batch rows x one K-half (2048 float4). 24 outputs split 8 ways:
// wave w x lane-half h handles phi rows w*6 + h*3 + {0,1,2} over the full
// K-half.
//
// R6 POST-MORTEM: every prior design had each wave re-read all 4 x rows ->
// 2.56 GB beyond-L1 traffic, L2-overflowing (32 MB/XCD working set) -> served
// by Infinity Cache at ~10-12 TB/s -> the universal ~210-270 us plateau.
//
// THIS DESIGN: x staged to LDS once per block (wave w stages row w,
// global->reg->LDS, double-buffered, T14 async split: next chunk's loads are
// issued BEFORE consuming the current chunk so HBM latency hides under the
// 8x48 FMA consume phase). ssq folded into staging (row w owned by wave w,
// no dynamic register indexing). All waves consume all 4 rows from LDS;
// lane-halves read identical addresses (same-address broadcast = free).
// x beyond-L1 traffic: 256 MB compulsory. phi: 1.5 GB, L2-resident.
// ---------------------------------------------------------------------------
__global__ __launch_bounds__(256, 4) void proj_kernel(
    const float* __restrict__ x,
    const float* __restrict__ phiws,
    float* __restrict__ dots_part)   // [2][B_ROWS][25]
{
    const float4* __restrict__ x4   = reinterpret_cast<const float4*>(x);
    const float4* __restrict__ phi4 = reinterpret_cast<const float4*>(phiws);

    const int bid  = blockIdx.x;
    const int kb   = bid & 1;            // K-half
    const int b0   = (bid >> 1) * 4;     // first batch row
    const int wave = threadIdx.x >> 6;
    const int lane = threadIdx.x & 63;
    const int half = lane >> 5;          // lane-half within wave
    const int l31  = lane & 31;

    __shared__ float4 xs[2][4][256];     // [buf][row][chunk float4] = 32 KB
    __shared__ float  red[4][2][12];     // [wave][half][r*3+j]
    __shared__ float  redss[4];          // ssq per row (owned by wave==row)

    const int kbase = kb * 2048;         // float4 index where this K-half starts

    // wave w stages batch row w: per chunk, lane loads 4 float4s
    const float4* __restrict__ srcw    = x4 + (size_t)(b0 + wave) * NC4 + kbase + lane;
    const float4* __restrict__ phibase = phi4 + (size_t)(wave * 6 + half * 3) * NC4 + kbase + l31;

    float acc[4][3];                     // [batch row][phi row j]
#pragma unroll
    for (int r = 0; r < 4; ++r)
#pragma unroll
        for (int j = 0; j < 3; ++j) acc[r][j] = 0.f;
    float ssq = 0.f;                     // sum x^2 of row `wave` (staging pass)

    // ---- prologue: stage chunk 0 ----
    {
        float4 st[4];
#pragma unroll
        for (int i = 0; i < 4; ++i) st[i] = srcw[i * 64];
#pragma unroll
        for (int i = 0; i < 4; ++i) {
            ssq += st[i].x*st[i].x + st[i].y*st[i].y + st[i].z*st[i].z + st[i].w*st[i].w;
            xs[0][wave][i * 64 + lane] = st[i];
        }
    }
    __syncthreads();

    int cur = 0;
    for (int c = 0; c < 8; ++c) {
        // ---- issue next chunk's global loads (in flight during consume) ----
        float4 nx[4];
        if (c < 7) {
#pragma unroll
            for (int i = 0; i < 4; ++i)
                nx[i] = srcw[(c + 1) * 256 + i * 64];
        }

        // ---- consume chunk c from xs[cur] ----
        const float4* __restrict__ xl = &xs[cur][0][0];
        const float4* __restrict__ pb = phibase + c * 256;
#pragma unroll
        for (int u = 0; u < 8; ++u) {
            const float4 xv0 = xl[0 * 256 + u * 32 + l31];
            const float4 xv1 = xl[1 * 256 + u * 32 + l31];
            const float4 xv2 = xl[2 * 256 + u * 32 + l31];
            const float4 xv3 = xl[3 * 256 + u * 32 + l31];
            const float4 p0  = pb[(size_t)0 * NC4 + u * 32];
            const float4 p1  = pb[(size_t)1 * NC4 + u * 32];
            const float4 p2  = pb[(size_t)2 * NC4 + u * 32];

            acc[0][0] += xv0.x*p0.x + xv0.y*p0.y + xv0.z*p0.z + xv0.w*p0.w;
            acc[1][0] += xv1.x*p0.x + xv1.y*p0.y + xv1.z*p0.z + xv1.w*p0.w;
            acc[2][0] += xv2.x*p0.x + xv2.y*p0.y + xv2.z*p0.z + xv2.w*p0.w;
            acc[3][0] += xv3.x*p0.x + xv3.y*p0.y + xv3.z*p0.z + xv3.w*p0.w;

            acc[0][1] += xv0.x*p1.x + xv0.y*p1.y + xv0.z*p1.z + xv0.w*p1.w;
            acc[1][1] += xv1.x*p1.x + xv1.y*p1.y + xv1.z*p1.z + xv1.w*p1.w;
            acc[2][1] += xv2.x*p1.x + xv2.y*p1.y + xv2.z*p1.z + xv2.w*p1.w;
            acc[3][1] += xv3.x*p1.x + xv3.y*p1.y + xv3.z*p1.z + xv3.w*p1.w;

            acc[0][2] += xv0.x*p2.x + xv0.y*p2.y + xv0.z*p2.z + xv0.w*p2.w;
            acc[1][2] += xv1.x*p2.x + xv1.y*p2.y + xv1.z*p2.z + xv1.w*p2.w;
            acc[2][2] += xv2.x*p2.x + xv2.y*p2.y + xv2.z*p2.z + xv2.w*p2.w;
            acc[3][2] += xv3.x*p2.x + xv3.y*p2.y + xv3.z*p2.z + xv3.w*p2.w;
        }

        // ---- write staged regs to the other buffer (after consume) ----
        if (c < 7) {
#pragma unroll
            for (int i = 0; i < 4; ++i) {
                ssq += nx[i].x*nx[i].x + nx[i].y*nx[i].y + nx[i].z*nx[i].z + nx[i].w*nx[i].w;
                xs[cur ^ 1][wave][i * 64 + lane] = nx[i];
            }
        }
        __syncthreads();     // next buffer visible; all waves done reading cur
        cur ^= 1;
    }

    // butterfly reduce dots within each 32-lane half (each half covers the
    // full K-half for its 3 phi rows)
#pragma unroll
    for (int r = 0; r < 4; ++r)
#pragma unroll
        for (int j = 0; j < 3; ++j) {
            float v = acc[r][j];
#pragma unroll
            for (int off = 16; off > 0; off >>= 1)
                v += __shfl_xor(v, off, 64);
            acc[r][j] = v;
        }
    // ssq staged across all 64 lanes of wave
#pragma unroll
    for (int off = 32; off > 0; off >>= 1)
        ssq += __shfl_xor(ssq, off, 64);

    if (l31 == 0) {
#pragma unroll
        for (int r = 0; r < 4; ++r)
#pragma unroll
            for (int j = 0; j < 3; ++j)
                red[wave][half][r * 3 + j] = acc[r][j];
    }
    if (lane == 0) redss[wave] = ssq;
    __syncthreads();

    // final gather; 100 threads -> dots_part[kb][4 rows][25]
    const int t = threadIdx.x;
    if (t < 100) {
        const int r = t / 25, o = t % 25;
        float s;
        if (o < 24) {
            const int w  = o / 6;
            const int hf = (o % 6) / 3;
            const int j  = o % 3;
            s = red[w][hf][r * 3 + j];
        } else {
            s = redss[r];                // ssq of row r staged by wave r
        }
        dots_part[((size_t)kb * B_ROWS + (b0 + r)) * 25 + o] = s;
    }
}

// ---------------------------------------------------------------------------
// Kernel 2: per-row finalize: sum K-halves, rms factor, softmax, 2*sigmoid,
// Sinkhorn(20).
// dots layout: [0..3]=pre, [4..7]=post, [8..23]=res, [24]=ssq
// params layout: [0..3]=H_pre, [4..7]=H_post, [8..23]=M (row-major 4x4)
// ---------------------------------------------------------------------------
__global__ void finalize_kernel(
    const float* __restrict__ dots_part,
    const float* __restrict__ b_pre,
    const float* __restrict__ b_post,
    const float* __restrict__ b_res,
    const float* __restrict__ alpha_pre,
    const float* __restrict__ alpha_post,
    const float* __restrict__ alpha_res,
    float* __restrict__ params)
{
    const int row = blockIdx.x * blockDim.x + threadIdx.x;
    if (row >= B_ROWS) return;

    const float* d0 = dots_part + (size_t)row * 25;
    const float* d1 = dots_part + ((size_t)B_ROWS + row) * 25;
    float d[25];
#pragma unroll
    for (int o = 0; o < 25; ++o) d[o] = d0[o] + d1[o];

    const float inv_rms = rsqrtf(d[24] * (1.f / (float)NC) + 1e-8f);
    const float ap  = alpha_pre[0];
    const float apo = alpha_post[0];
    const float ar  = alpha_res[0];

    // softmax(h_pre)
    float hp[4];
    float mx = -1e30f;
#pragma unroll
    for (int j = 0; j < 4; ++j) {
        hp[j] = ap * d[j] * inv_rms + b_pre[j];
        mx = fmaxf(mx, hp[j]);
    }
    float e[4], s = 0.f;
#pragma unroll
    for (int j = 0; j < 4; ++j) { e[j] = expf(hp[j] - mx); s += e[j]; }
    float Hpre[4];
#pragma unroll
    for (int j = 0; j < 4; ++j) Hpre[j] = e[j] / s;

    // 2*sigmoid(h_post)
    float Hpost[4];
#pragma unroll
    for (int j = 0; j < 4; ++j) {
        const float h = apo * d[4 + j] * inv_rms + b_post[j];
        Hpost[j] = 2.f / (1.f + expf(-h));
    }

    // Sinkhorn on exp(h_res)
    float M[16];
#pragma unroll
    for (int k = 0; k < 16; ++k)
        M[k] = expf(ar * d[8 + k] * inv_rms + b_res[k]);

    for (int it = 0; it < 20; ++it) {
#pragma unroll
        for (int i = 0; i < 4; ++i) {
            const float rs = M[i*4+0] + M[i*4+1] + M[i*4+2] + M[i*4+3] + 1e-8f;
#pragma unroll
            for (int j = 0; j < 4; ++j) M[i*4+j] = M[i*4+j] / rs;
        }
#pragma unroll
        for (int j = 0; j < 4; ++j) {
            const float cs = M[0*4+j] + M[1*4+j] + M[2*4+j] + M[3*4+j] + 1e-8f;
#pragma unroll
            for (int i = 0; i < 4; ++i) M[i*4+j] = M[i*4+j] / cs;
        }
    }

    float* p = params + (size_t)row * 24;
#pragma unroll
    for (int j = 0; j < 4; ++j)  p[j]     = Hpre[j];
#pragma unroll
    for (int j = 0; j < 4; ++j)  p[4 + j] = Hpost[j];
#pragma unroll
    for (int k = 0; k < 16; ++k) p[8 + k] = M[k];
}

// ---------------------------------------------------------------------------
// Kernel 3: output. One block per batch row; x row held in registers
// (64 floats/thread), block-reduced RMS of x_agg, then fused epilogue.
// ---------------------------------------------------------------------------
__global__ __launch_bounds__(256, 2) void out_kernel(
    const float* __restrict__ x,
    const float* __restrict__ w,
    const float* __restrict__ params,
    float* __restrict__ out)
{
    const float4* __restrict__ x4 = reinterpret_cast<const float4*>(x);
    const float4* __restrict__ w4 = reinterpret_cast<const float4*>(w);
    float4* __restrict__ out4 = reinterpret_cast<float4*>(out);

    const int b = blockIdx.x;
    const float* __restrict__ p = params + (size_t)b * 24;

    float Hpre[4], Hpost[4], M[16];
#pragma unroll
    for (int j = 0; j < 4; ++j)  Hpre[j]  = p[j];
#pragma unroll
    for (int j = 0; j < 4; ++j)  Hpost[j] = p[4 + j];
#pragma unroll
    for (int k = 0; k < 16; ++k) M[k]     = p[8 + k];

    const int t = threadIdx.x;
    const size_t base = (size_t)b * NC4;

    float4 xv[4][4];  // [u][stream]
    float4 agg[4];
    float ssq = 0.f;

#pragma unroll
    for (int u = 0; u < 4; ++u) {
        const int c4 = u * 256 + t;
#pragma unroll
        for (int n = 0; n < 4; ++n)
            xv[u][n] = x4[base + (size_t)n * C4 + c4];

        float4 a;
        a.x = Hpre[0]*xv[u][0].x + Hpre[1]*xv[u][1].x + Hpre[2]*xv[u][2].x + Hpre[3]*xv[u][3].x;
        a.y = Hpre[0]*xv[u][0].y + Hpre[1]*xv[u][1].y + Hpre[2]*xv[u][2].y + Hpre[3]*xv[u][3].y;
        a.z = Hpre[0]*xv[u][0].z + Hpre[1]*xv[u][1].z + Hpre[2]*xv[u][2].z + Hpre[3]*xv[u][3].z;
        a.w = Hpre[0]*xv[u][0].w + Hpre[1]*xv[u][1].w + Hpre[2]*xv[u][2].w + Hpre[3]*xv[u][3].w;
        agg[u] = a;
        ssq += a.x*a.x + a.y*a.y + a.z*a.z + a.w*a.w;
    }

    // block-wide sum of ssq
#pragma unroll
    for (int off = 32; off > 0; off >>= 1)
        ssq += __shfl_xor(ssq, off, 64);
    __shared__ float red[4];
    if ((t & 63) == 0) red[t >> 6] = ssq;
    __syncthreads();
    const float total = red[0] + red[1] + red[2] + red[3];
    const float inv = rsqrtf(total * (1.f / (float)C_DIM) + 1e-5f);

#pragma unroll
    for (int u = 0; u < 4; ++u) {
        const int c4 = u * 256 + t;
        const float4 wv = w4[c4];
        float4 y;
        y.x = agg[u].x * inv * wv.x;
        y.y = agg[u].y * inv * wv.y;
        y.z = agg[u].z * inv * wv.z;
        y.w = agg[u].w * inv * wv.w;

#pragma unroll
        for (int i = 0; i < 4; ++i) {
            float4 o;
            o.x = Hpost[i]*y.x + M[i*4+0]*xv[u][0].x + M[i*4+1]*xv[u][1].x
                               + M[i*4+2]*xv[u][2].x + M[i*4+3]*xv[u][3].x;
            o.y = Hpost[i]*y.y + M[i*4+0]*xv[u][0].y + M[i*4+1]*xv[u][1].y
                               + M[i*4+2]*xv[u][2].y + M[i*4+3]*xv[u][3].y;
            o.z = Hpost[i]*y.z + M[i*4+0]*xv[u][0].z + M[i*4+1]*xv[u][1].z
                               + M[i*4+2]*xv[u][2].z + M[i*4+3]*xv[u][3].z;
            o.w = Hpost[i]*y.w + M[i*4+0]*xv[u][0].w + M[i*4+1]*xv[u][1].w
                               + M[i*4+2]*xv[u][2].w + M[i*4+3]*xv[u][3].w;
            out4[base + (size_t)i * C4 + c4] = o;
        }
    }
}

// ---------------------------------------------------------------------------
extern "C" void kernel_launch(void* const* d_in, const int* in_sizes, int n_in,
                              void* d_out, int out_size, void* d_ws, size_t ws_size,
                              hipStream_t stream) {
    const float* x        = (const float*)d_in[0];
    const float* w        = (const float*)d_in[1];
    const float* phi_pre  = (const float*)d_in[2];
    const float* phi_post = (const float*)d_in[3];
    const float* phi_res  = (const float*)d_in[4];
    const float* b_pre    = (const float*)d_in[5];
    const float* b_post   = (const float*)d_in[6];
    const float* b_res    = (const float*)d_in[7];
    const float* a_pre    = (const float*)d_in[8];
    const float* a_post   = (const float*)d_in[9];
    const float* a_res    = (const float*)d_in[10];
    float* out = (float*)d_out;

    float* dots_part = (float*)d_ws;                        // [2][4096][25]
    float* params    = dots_part + (size_t)2 * B_ROWS * 25; // [4096][24]
    float* phiws     = params + (size_t)B_ROWS * 24;        // [24][16384]

    hipLaunchKernelGGL(repack_kernel, dim3((24 * NC4 + 255) / 256), dim3(256), 0, stream,
                       (const float4*)phi_pre, (const float4*)phi_post,
                       (const float4*)phi_res, (float4*)phiws);
    hipLaunchKernelGGL(proj_kernel, dim3(B_ROWS / 2), dim3(256), 0, stream,
                       x, phiws, dots_part);
    hipLaunchKernelGGL(finalize_kernel, dim3(B_ROWS / 256), dim3(256), 0, stream,
                       dots_part, b_pre, b_post, b_res, a_pre, a_post, a_res, params);
    hipLaunchKernelGGL(out_kernel, dim3(B_ROWS), dim3(256), 0, stream,
                       x, w, params, out);
}

// Round 8
// 233.504 us; speedup vs baseline: 4.8393x; 4.8393x over previous
//
#include <hip/hip_runtime.h>
#include <math.h>

#define B_ROWS 4096
#define NSTR 4
#define C_DIM 4096
#define NC 16384      // NSTR*C_DIM
#define NC4 4096      // NC/4 (float4 per batch row)
#define C4 1024       // C_DIM/4 (float4 per stream)

// async global->LDS DMA, 16B per lane. LDS dest must be wave-uniform base;
// lane l writes base + l*16. Global src is per-lane.
#define ASYNC_COPY16(g, l)                                                     \
    __builtin_amdgcn_global_load_lds(                                         \
        (const __attribute__((address_space(1))) void*)(g),                   \
        (__attribute__((address_space(3))) void*)(l), 16, 0, 0)

// ---------------------------------------------------------------------------
// Kernel 0: repack phi into one contiguous [24][16384] buffer.
// Row order: [pre0..3, post0..3, res0..15]
// ---------------------------------------------------------------------------
__global__ void repack_kernel(
    const float4* __restrict__ pre4,
    const float4* __restrict__ post4,
    const float4* __restrict__ res4,
    float4* __restrict__ phiws4)
{
    const int idx = blockIdx.x * blockDim.x + threadIdx.x;   // 0 .. 24*4096-1
    if (idx >= 24 * NC4) return;
    const int row = idx / NC4;
    const int k4  = idx % NC4;
    float4 v;
    if (row < 4)        v = pre4[row * NC4 + k4];
    else if (row < 8)   v = post4[(row - 4) * NC4 + k4];
    else                v = res4[(row - 8) * NC4 + k4];
    phiws4[idx] = v;
}

// ---------------------------------------------------------------------------
// Kernel 1: projections. Grid = (B_ROWS/4) x 2 K-halves -> 2048 blocks.
// Block = 4 batch rows x one K-half (2048 float4). 24 outputs split 8 ways:
// wave w x lane-half h handles phi rows w*6 + h*3 + {0,1,2} over the full
// K-half.
//
// R7 POST-MORTEM: reg-staged x + fully-unrolled consume let the scheduler
// hoist 24 phi loads (96 regs) over nx[16]+acc -> scratch spill (2.5 GB
// writes, VALUBusy 7%). FIX:
//  (1) x staged via global_load_lds (DMA, zero VGPRs in staging path),
//      issued one full chunk ahead -> ~768 FMA-cycles cover HBM latency;
//      barrier's vmcnt(0) drain guarantees visibility.
//  (2) consume loop "#pragma unroll 2": max ~56 live load temps, no hoist
//      blowup; 6 phi (L2-hit ~200cy) + 8 LDS reads in flight per segment,
//      covered by 4 waves/SIMD.
//  (3) ssq folded into consume via wave-uniform scalar branch (readfirstlane)
//      picking the wave's own row; lane-halves read identical LDS addresses
//      (broadcast), so ssq reduces over one 32-lane half only.
// Traffic: x 256MB HBM; phi 1.5GB L2 (phi = 1.5MB, L2-resident per XCD);
// LDS 2GB @ ~78TB/s. All ~25-45us, overlapping.
// ---------------------------------------------------------------------------
__global__ __launch_bounds__(256, 4) void proj_kernel(
    const float* __restrict__ x,
    const float* __restrict__ phiws,
    float* __restrict__ dots_part)   // [2][B_ROWS][25]
{
    const float4* __restrict__ x4   = reinterpret_cast<const float4*>(x);
    const float4* __restrict__ phi4 = reinterpret_cast<const float4*>(phiws);

    const int bid  = blockIdx.x;
    const int kb   = bid & 1;            // K-half
    const int b0   = (bid >> 1) * 4;     // first batch row
    const int wave = threadIdx.x >> 6;
    const int lane = threadIdx.x & 63;
    const int half = lane >> 5;          // lane-half within wave
    const int l31  = lane & 31;
    const int wv   = __builtin_amdgcn_readfirstlane(wave);  // SGPR wave id

    __shared__ float4 xs[2][4][256];     // [buf][row][float4] = 32 KB
    __shared__ float  red[4][2][12];     // [wave][half][r*3+j]
    __shared__ float  redss[4];          // ssq per row (owned by wave==row)

    const int kbase = kb * 2048;         // float4 index where this K-half starts

    // wave w stages batch row w; per chunk each lane DMAs 4 float4s
    const float4* __restrict__ srcw    = x4 + (size_t)(b0 + wave) * NC4 + kbase + lane;
    const float4* __restrict__ phibase = phi4 + (size_t)(wave * 6 + half * 3) * NC4 + kbase + l31;

    float acc[4][3];                     // [batch row][phi row j]
#pragma unroll
    for (int r = 0; r < 4; ++r)
#pragma unroll
        for (int j = 0; j < 3; ++j) acc[r][j] = 0.f;
    float ssq = 0.f;                     // sum x^2 of row `wave`

    // ---- prologue: DMA chunk 0 into buffer 0 ----
#pragma unroll
    for (int i = 0; i < 4; ++i)
        ASYNC_COPY16(srcw + i * 64, &xs[0][wave][i * 64]);
    __syncthreads();                     // drains vmcnt -> chunk 0 visible

    int cur = 0;
#pragma unroll 1
    for (int c = 0; c < 8; ++c) {
        // ---- DMA next chunk into the other buffer (in flight during consume)
        if (c < 7) {
#pragma unroll
            for (int i = 0; i < 4; ++i)
                ASYNC_COPY16(srcw + (c + 1) * 256 + i * 64,
                             &xs[cur ^ 1][wave][i * 64]);
        }

        // ---- consume chunk c from xs[cur] ----
        const float4* __restrict__ xl = &xs[cur][0][0];
        const float4* __restrict__ pb = phibase + c * 256;
#pragma unroll 2
        for (int u = 0; u < 8; ++u) {
            const float4 xv0 = xl[0 * 256 + u * 32 + l31];
            const float4 xv1 = xl[1 * 256 + u * 32 + l31];
            const float4 xv2 = xl[2 * 256 + u * 32 + l31];
            const float4 xv3 = xl[3 * 256 + u * 32 + l31];
            const float4 p0  = pb[(size_t)0 * NC4 + u * 32];
            const float4 p1  = pb[(size_t)1 * NC4 + u * 32];
            const float4 p2  = pb[(size_t)2 * NC4 + u * 32];

            acc[0][0] += xv0.x*p0.x + xv0.y*p0.y + xv0.z*p0.z + xv0.w*p0.w;
            acc[1][0] += xv1.x*p0.x + xv1.y*p0.y + xv1.z*p0.z + xv1.w*p0.w;
            acc[2][0] += xv2.x*p0.x + xv2.y*p0.y + xv2.z*p0.z + xv2.w*p0.w;
            acc[3][0] += xv3.x*p0.x + xv3.y*p0.y + xv3.z*p0.z + xv3.w*p0.w;

            acc[0][1] += xv0.x*p1.x + xv0.y*p1.y + xv0.z*p1.z + xv0.w*p1.w;
            acc[1][1] += xv1.x*p1.x + xv1.y*p1.y + xv1.z*p1.z + xv1.w*p1.w;
            acc[2][1] += xv2.x*p1.x + xv2.y*p1.y + xv2.z*p1.z + xv2.w*p1.w;
            acc[3][1] += xv3.x*p1.x + xv3.y*p1.y + xv3.z*p1.z + xv3.w*p1.w;

            acc[0][2] += xv0.x*p2.x + xv0.y*p2.y + xv0.z*p2.z + xv0.w*p2.w;
            acc[1][2] += xv1.x*p2.x + xv1.y*p2.y + xv1.z*p2.z + xv1.w*p2.w;
            acc[2][2] += xv2.x*p2.x + xv2.y*p2.y + xv2.z*p2.z + xv2.w*p2.w;
            acc[3][2] += xv3.x*p2.x + xv3.y*p2.y + xv3.z*p2.z + xv3.w*p2.w;

            // ssq of this wave's own row (wave-uniform scalar branch)
            float4 xw;
            if      (wv == 0) xw = xv0;
            else if (wv == 1) xw = xv1;
            else if (wv == 2) xw = xv2;
            else              xw = xv3;
            ssq += xw.x*xw.x + xw.y*xw.y + xw.z*xw.z + xw.w*xw.w;
        }

        __syncthreads();     // next DMA chunk visible; all waves done with cur
        cur ^= 1;
    }

    // butterfly reduce within each 32-lane half (each half covers the full
    // K-half for its 3 phi rows; both halves hold identical x data, so ssq
    // also reduces within one half)
#pragma unroll
    for (int r = 0; r < 4; ++r)
#pragma unroll
        for (int j = 0; j < 3; ++j) {
            float v = acc[r][j];
#pragma unroll
            for (int off = 16; off > 0; off >>= 1)
                v += __shfl_xor(v, off, 64);
            acc[r][j] = v;
        }
#pragma unroll
    for (int off = 16; off > 0; off >>= 1)
        ssq += __shfl_xor(ssq, off, 64);

    if (l31 == 0) {
#pragma unroll
        for (int r = 0; r < 4; ++r)
#pragma unroll
            for (int j = 0; j < 3; ++j)
                red[wave][half][r * 3 + j] = acc[r][j];
    }
    if (lane == 0) redss[wave] = ssq;    // half-0 copy
    __syncthreads();

    // final gather; 100 threads -> dots_part[kb][4 rows][25]
    const int t = threadIdx.x;
    if (t < 100) {
        const int r = t / 25, o = t % 25;
        float s;
        if (o < 24) {
            const int w  = o / 6;
            const int hf = (o % 6) / 3;
            const int j  = o % 3;
            s = red[w][hf][r * 3 + j];
        } else {
            s = redss[r];                // ssq of row r staged by wave r
        }
        dots_part[((size_t)kb * B_ROWS + (b0 + r)) * 25 + o] = s;
    }
}

// ---------------------------------------------------------------------------
// Kernel 2: per-row finalize: sum K-halves, rms factor, softmax, 2*sigmoid,
// Sinkhorn(20).
// dots layout: [0..3]=pre, [4..7]=post, [8..23]=res, [24]=ssq
// params layout: [0..3]=H_pre, [4..7]=H_post, [8..23]=M (row-major 4x4)
// ---------------------------------------------------------------------------
__global__ void finalize_kernel(
    const float* __restrict__ dots_part,
    const float* __restrict__ b_pre,
    const float* __restrict__ b_post,
    const float* __restrict__ b_res,
    const float* __restrict__ alpha_pre,
    const float* __restrict__ alpha_post,
    const float* __restrict__ alpha_res,
    float* __restrict__ params)
{
    const int row = blockIdx.x * blockDim.x + threadIdx.x;
    if (row >= B_ROWS) return;

    const float* d0 = dots_part + (size_t)row * 25;
    const float* d1 = dots_part + ((size_t)B_ROWS + row) * 25;
    float d[25];
#pragma unroll
    for (int o = 0; o < 25; ++o) d[o] = d0[o] + d1[o];

    const float inv_rms = rsqrtf(d[24] * (1.f / (float)NC) + 1e-8f);
    const float ap  = alpha_pre[0];
    const float apo = alpha_post[0];
    const float ar  = alpha_res[0];

    // softmax(h_pre)
    float hp[4];
    float mx = -1e30f;
#pragma unroll
    for (int j = 0; j < 4; ++j) {
        hp[j] = ap * d[j] * inv_rms + b_pre[j];
        mx = fmaxf(mx, hp[j]);
    }
    float e[4], s = 0.f;
#pragma unroll
    for (int j = 0; j < 4; ++j) { e[j] = expf(hp[j] - mx); s += e[j]; }
    float Hpre[4];
#pragma unroll
    for (int j = 0; j < 4; ++j) Hpre[j] = e[j] / s;

    // 2*sigmoid(h_post)
    float Hpost[4];
#pragma unroll
    for (int j = 0; j < 4; ++j) {
        const float h = apo * d[4 + j] * inv_rms + b_post[j];
        Hpost[j] = 2.f / (1.f + expf(-h));
    }

    // Sinkhorn on exp(h_res)
    float M[16];
#pragma unroll
    for (int k = 0; k < 16; ++k)
        M[k] = expf(ar * d[8 + k] * inv_rms + b_res[k]);

    for (int it = 0; it < 20; ++it) {
#pragma unroll
        for (int i = 0; i < 4; ++i) {
            const float rs = M[i*4+0] + M[i*4+1] + M[i*4+2] + M[i*4+3] + 1e-8f;
#pragma unroll
            for (int j = 0; j < 4; ++j) M[i*4+j] = M[i*4+j] / rs;
        }
#pragma unroll
        for (int j = 0; j < 4; ++j) {
            const float cs = M[0*4+j] + M[1*4+j] + M[2*4+j] + M[3*4+j] + 1e-8f;
#pragma unroll
            for (int i = 0; i < 4; ++i) M[i*4+j] = M[i*4+j] / cs;
        }
    }

    float* p = params + (size_t)row * 24;
#pragma unroll
    for (int j = 0; j < 4; ++j)  p[j]     = Hpre[j];
#pragma unroll
    for (int j = 0; j < 4; ++j)  p[4 + j] = Hpost[j];
#pragma unroll
    for (int k = 0; k < 16; ++k) p[8 + k] = M[k];
}

// ---------------------------------------------------------------------------
// Kernel 3: output. One block per batch row; x row held in registers
// (64 floats/thread), block-reduced RMS of x_agg, then fused epilogue.
// ---------------------------------------------------------------------------
__global__ __launch_bounds__(256, 2) void out_kernel(
    const float* __restrict__ x,
    const float* __restrict__ w,
    const float* __restrict__ params,
    float* __restrict__ out)
{
    const float4* __restrict__ x4 = reinterpret_cast<const float4*>(x);
    const float4* __restrict__ w4 = reinterpret_cast<const float4*>(w);
    float4* __restrict__ out4 = reinterpret_cast<float4*>(out);

    const int b = blockIdx.x;
    const float* __restrict__ p = params + (size_t)b * 24;

    float Hpre[4], Hpost[4], M[16];
#pragma unroll
    for (int j = 0; j < 4; ++j)  Hpre[j]  = p[j];
#pragma unroll
    for (int j = 0; j < 4; ++j)  Hpost[j] = p[4 + j];
#pragma unroll
    for (int k = 0; k < 16; ++k) M[k]     = p[8 + k];

    const int t = threadIdx.x;
    const size_t base = (size_t)b * NC4;

    float4 xv[4][4];  // [u][stream]
    float4 agg[4];
    float ssq = 0.f;

#pragma unroll
    for (int u = 0; u < 4; ++u) {
        const int c4 = u * 256 + t;
#pragma unroll
        for (int n = 0; n < 4; ++n)
            xv[u][n] = x4[base + (size_t)n * C4 + c4];

        float4 a;
        a.x = Hpre[0]*xv[u][0].x + Hpre[1]*xv[u][1].x + Hpre[2]*xv[u][2].x + Hpre[3]*xv[u][3].x;
        a.y = Hpre[0]*xv[u][0].y + Hpre[1]*xv[u][1].y + Hpre[2]*xv[u][2].y + Hpre[3]*xv[u][3].y;
        a.z = Hpre[0]*xv[u][0].z + Hpre[1]*xv[u][1].z + Hpre[2]*xv[u][2].z + Hpre[3]*xv[u][3].z;
        a.w = Hpre[0]*xv[u][0].w + Hpre[1]*xv[u][1].w + Hpre[2]*xv[u][2].w + Hpre[3]*xv[u][3].w;
        agg[u] = a;
        ssq += a.x*a.x + a.y*a.y + a.z*a.z + a.w*a.w;
    }

    // block-wide sum of ssq
#pragma unroll
    for (int off = 32; off > 0; off >>= 1)
        ssq += __shfl_xor(ssq, off, 64);
    __shared__ float red[4];
    if ((t & 63) == 0) red[t >> 6] = ssq;
    __syncthreads();
    const float total = red[0] + red[1] + red[2] + red[3];
    const float inv = rsqrtf(total * (1.f / (float)C_DIM) + 1e-5f);

#pragma unroll
    for (int u = 0; u < 4; ++u) {
        const int c4 = u * 256 + t;
        const float4 wv = w4[c4];
        float4 y;
        y.x = agg[u].x * inv * wv.x;
        y.y = agg[u].y * inv * wv.y;
        y.z = agg[u].z * inv * wv.z;
        y.w = agg[u].w * inv * wv.w;

#pragma unroll
        for (int i = 0; i < 4; ++i) {
            float4 o;
            o.x = Hpost[i]*y.x + M[i*4+0]*xv[u][0].x + M[i*4+1]*xv[u][1].x
                               + M[i*4+2]*xv[u][2].x + M[i*4+3]*xv[u][3].x;
            o.y = Hpost[i]*y.y + M[i*4+0]*xv[u][0].y + M[i*4+1]*xv[u][1].y
                               + M[i*4+2]*xv[u][2].y + M[i*4+3]*xv[u][3].y;
            o.z = Hpost[i]*y.z + M[i*4+0]*xv[u][0].z + M[i*4+1]*xv[u][1].z
                               + M[i*4+2]*xv[u][2].z + M[i*4+3]*xv[u][3].z;
            o.w = Hpost[i]*y.w + M[i*4+0]*xv[u][0].w + M[i*4+1]*xv[u][1].w
                               + M[i*4+2]*xv[u][2].w + M[i*4+3]*xv[u][3].w;
            out4[base + (size_t)i * C4 + c4] = o;
        }
    }
}

// ---------------------------------------------------------------------------
extern "C" void kernel_launch(void* const* d_in, const int* in_sizes, int n_in,
                              void* d_out, int out_size, void* d_ws, size_t ws_size,
                              hipStream_t stream) {
    const float* x        = (const float*)d_in[0];
    const float* w        = (const float*)d_in[1];
    const float* phi_pre  = (const float*)d_in[2];
    const float* phi_post = (const float*)d_in[3];
    const float* phi_res  = (const float*)d_in[4];
    const float* b_pre    = (const float*)d_in[5];
    const float* b_post   = (const float*)d_in[6];
    const float* b_res    = (const float*)d_in[7];
    const float* a_pre    = (const float*)d_in[8];
    const float* a_post   = (const float*)d_in[9];
    const float* a_res    = (const float*)d_in[10];
    float* out = (float*)d_out;

    float* dots_part = (float*)d_ws;                        // [2][4096][25]
    float* params    = dots_part + (size_t)2 * B_ROWS * 25; // [4096][24]
    float* phiws     = params + (size_t)B_ROWS * 24;        // [24][16384]

    hipLaunchKernelGGL(repack_kernel, dim3((24 * NC4 + 255) / 256), dim3(256), 0, stream,
                       (const float4*)phi_pre, (const float4*)phi_post,
                       (const float4*)phi_res, (float4*)phiws);
    hipLaunchKernelGGL(proj_kernel, dim3(B_ROWS / 2), dim3(256), 0, stream,
                       x, phiws, dots_part);
    hipLaunchKernelGGL(finalize_kernel, dim3(B_ROWS / 256), dim3(256), 0, stream,
                       dots_part, b_pre, b_post, b_res, a_pre, a_post, a_res, params);
    hipLaunchKernelGGL(out_kernel, dim3(B_ROWS), dim3(256), 0, stream,
                       x, w, params, out);
}

// Round 9
// 228.261 us; speedup vs baseline: 4.9505x; 1.0230x over previous
//
#include <hip/hip_runtime.h>
#include <math.h>

#define B_ROWS 4096
#define NSTR 4
#define C_DIM 4096
#define NC 16384      // NSTR*C_DIM
#define NC4 4096      // NC/4 (float4 per batch row)
#define C4 1024       // C_DIM/4 (float4 per stream)

// async global->LDS DMA, 16B per lane. LDS dest must be wave-uniform base;
// lane l writes base + l*16. Global src is per-lane.
#define ASYNC_COPY16(g, l)                                                     \
    __builtin_amdgcn_global_load_lds(                                         \
        (const __attribute__((address_space(1))) void*)(g),                   \
        (__attribute__((address_space(3))) void*)(l), 16, 0, 0)

// ---------------------------------------------------------------------------
// Kernel 0: repack phi into one contiguous [24][16384] buffer.
// Row order: [pre0..3, post0..3, res0..15]
// ---------------------------------------------------------------------------
__global__ void repack_kernel(
    const float4* __restrict__ pre4,
    const float4* __restrict__ post4,
    const float4* __restrict__ res4,
    float4* __restrict__ phiws4)
{
    const int idx = blockIdx.x * blockDim.x + threadIdx.x;   // 0 .. 24*4096-1
    if (idx >= 24 * NC4) return;
    const int row = idx / NC4;
    const int k4  = idx % NC4;
    float4 v;
    if (row < 4)        v = pre4[row * NC4 + k4];
    else if (row < 8)   v = post4[(row - 4) * NC4 + k4];
    else                v = res4[(row - 8) * NC4 + k4];
    phiws4[idx] = v;
}

// ---------------------------------------------------------------------------
// Kernel 1: projections. Grid = (B_ROWS/8) x 2 K-halves -> 1024 blocks of
// 512 threads (8 waves). Block = 8 batch rows x one K-half (2048 float4).
//
// R8 POST-MORTEM: proj ~145us vs ~55us floor. phi L2 traffic was 1.57 GB
// (768 KB per 4-row block) and the x stream keeps evicting phi from the
// 4MB/XCD L2 -> L3-latency phi loads inside the dependent chain with only
// 52 FMAs/u-step of cover. THIS DESIGN: 8 rows/block halves phi traffic
// (786 MB) and doubles FMA:phi-load ratio (96 FMAs per 3 phi loads).
//
// Wave w DMA-stages its own row w (global_load_lds, zero reg pressure) and
// computes phi rows 3w..3w+2 for ALL 8 rows; lanes cover 64 consecutive
// float4s per u-step (full-wave K coverage, butterfly over 64 lanes).
// ssq of row w: one extra LDS read at SGPR-uniform row offset (branchless,
// no dynamic register indexing). #pragma unroll 1 on u-loop (R7 lesson:
// full unroll lets the scheduler hoist all loads -> spill).
// Live floats ~ acc24 + p12 + xv/xw ~12 + addr ~10 = ~58 << 128 cap (512,4).
// LDS: 64 KB xs + 0.8 KB red -> 2 blocks/CU = 16 waves/CU.
// ---------------------------------------------------------------------------
__global__ __launch_bounds__(512, 4) void proj_kernel(
    const float* __restrict__ x,
    const float* __restrict__ phiws,
    float* __restrict__ dots_part)   // [2][B_ROWS][25]
{
    const float4* __restrict__ x4   = reinterpret_cast<const float4*>(x);
    const float4* __restrict__ phi4 = reinterpret_cast<const float4*>(phiws);

    const int bid  = blockIdx.x;
    const int kb   = bid & 1;            // K-half
    const int b0   = (bid >> 1) * 8;     // first batch row
    const int wave = threadIdx.x >> 6;   // 0..7
    const int lane = threadIdx.x & 63;
    const int wv   = __builtin_amdgcn_readfirstlane(wave);  // SGPR wave id

    __shared__ float4 xs[2][8][256];     // [buf][row][float4] = 64 KB
    __shared__ float  red[8][8][3];      // [wave][row][j]
    __shared__ float  redss[8];          // ssq per row (owned by wave==row)

    const int kbase = kb * 2048;         // float4 index where this K-half starts

    // wave w stages batch row w; per chunk each lane DMAs 4 float4s
    const float4* __restrict__ srcw    = x4 + (size_t)(b0 + wave) * NC4 + kbase + lane;
    // wave w's 3 phi rows
    const float4* __restrict__ phibase = phi4 + (size_t)(wave * 3) * NC4 + kbase + lane;

    float acc[8][3];                     // [batch row][phi row j]
#pragma unroll
    for (int r = 0; r < 8; ++r)
#pragma unroll
        for (int j = 0; j < 3; ++j) acc[r][j] = 0.f;
    float ssq = 0.f;                     // sum x^2 of row `wave`

    // ---- prologue: DMA chunk 0 into buffer 0 ----
#pragma unroll
    for (int i = 0; i < 4; ++i)
        ASYNC_COPY16(srcw + i * 64, &xs[0][wave][i * 64]);
    __syncthreads();                     // drains vmcnt -> chunk 0 visible

    int cur = 0;
#pragma unroll 1
    for (int c = 0; c < 8; ++c) {
        // ---- DMA next chunk into the other buffer (in flight during consume)
        if (c < 7) {
#pragma unroll
            for (int i = 0; i < 4; ++i)
                ASYNC_COPY16(srcw + (c + 1) * 256 + i * 64,
                             &xs[cur ^ 1][wave][i * 64]);
        }

        // ---- consume chunk c from xs[cur]: 4 u-steps of 64 float4s ----
        const float4* __restrict__ pb = phibase + c * 256;
#pragma unroll 1
        for (int u = 0; u < 4; ++u) {
            const int ki = u * 64 + lane;

            const float4 p0 = pb[(size_t)0 * NC4 + u * 64];
            const float4 p1 = pb[(size_t)1 * NC4 + u * 64];
            const float4 p2 = pb[(size_t)2 * NC4 + u * 64];

            // ssq of this wave's own row (SGPR-uniform row index)
            const float4 xw = xs[cur][wv][ki];
            ssq += xw.x*xw.x + xw.y*xw.y + xw.z*xw.z + xw.w*xw.w;

#pragma unroll
            for (int r = 0; r < 8; ++r) {
                const float4 xv = xs[cur][r][ki];
                acc[r][0] += xv.x*p0.x + xv.y*p0.y + xv.z*p0.z + xv.w*p0.w;
                acc[r][1] += xv.x*p1.x + xv.y*p1.y + xv.z*p1.z + xv.w*p1.w;
                acc[r][2] += xv.x*p2.x + xv.y*p2.y + xv.z*p2.z + xv.w*p2.w;
            }
        }

        __syncthreads();     // next DMA chunk visible; all waves done with cur
        cur ^= 1;
    }

    // butterfly reduce across all 64 lanes (lanes cover distinct K positions)
#pragma unroll
    for (int r = 0; r < 8; ++r)
#pragma unroll
        for (int j = 0; j < 3; ++j) {
            float v = acc[r][j];
#pragma unroll
            for (int off = 32; off > 0; off >>= 1)
                v += __shfl_xor(v, off, 64);
            acc[r][j] = v;
        }
#pragma unroll
    for (int off = 32; off > 0; off >>= 1)
        ssq += __shfl_xor(ssq, off, 64);

    if (lane == 0) {
#pragma unroll
        for (int r = 0; r < 8; ++r)
#pragma unroll
            for (int j = 0; j < 3; ++j)
                red[wave][r][j] = acc[r][j];
        redss[wave] = ssq;
    }
    __syncthreads();

    // final gather; 200 threads -> dots_part[kb][8 rows][25]
    const int t = threadIdx.x;
    if (t < 200) {
        const int r = t / 25, o = t % 25;
        float s;
        if (o < 24) s = red[o / 3][r][o % 3];   // phi row o handled by wave o/3
        else        s = redss[r];               // ssq of row r staged by wave r
        dots_part[((size_t)kb * B_ROWS + (b0 + r)) * 25 + o] = s;
    }
}

// ---------------------------------------------------------------------------
// Kernel 2: per-row finalize: sum K-halves, rms factor, softmax, 2*sigmoid,
// Sinkhorn(20).
// dots layout: [0..3]=pre, [4..7]=post, [8..23]=res, [24]=ssq
// params layout: [0..3]=H_pre, [4..7]=H_post, [8..23]=M (row-major 4x4)
// ---------------------------------------------------------------------------
__global__ void finalize_kernel(
    const float* __restrict__ dots_part,
    const float* __restrict__ b_pre,
    const float* __restrict__ b_post,
    const float* __restrict__ b_res,
    const float* __restrict__ alpha_pre,
    const float* __restrict__ alpha_post,
    const float* __restrict__ alpha_res,
    float* __restrict__ params)
{
    const int row = blockIdx.x * blockDim.x + threadIdx.x;
    if (row >= B_ROWS) return;

    const float* d0 = dots_part + (size_t)row * 25;
    const float* d1 = dots_part + ((size_t)B_ROWS + row) * 25;
    float d[25];
#pragma unroll
    for (int o = 0; o < 25; ++o) d[o] = d0[o] + d1[o];

    const float inv_rms = rsqrtf(d[24] * (1.f / (float)NC) + 1e-8f);
    const float ap  = alpha_pre[0];
    const float apo = alpha_post[0];
    const float ar  = alpha_res[0];

    // softmax(h_pre)
    float hp[4];
    float mx = -1e30f;
#pragma unroll
    for (int j = 0; j < 4; ++j) {
        hp[j] = ap * d[j] * inv_rms + b_pre[j];
        mx = fmaxf(mx, hp[j]);
    }
    float e[4], s = 0.f;
#pragma unroll
    for (int j = 0; j < 4; ++j) { e[j] = expf(hp[j] - mx); s += e[j]; }
    float Hpre[4];
#pragma unroll
    for (int j = 0; j < 4; ++j) Hpre[j] = e[j] / s;

    // 2*sigmoid(h_post)
    float Hpost[4];
#pragma unroll
    for (int j = 0; j < 4; ++j) {
        const float h = apo * d[4 + j] * inv_rms + b_post[j];
        Hpost[j] = 2.f / (1.f + expf(-h));
    }

    // Sinkhorn on exp(h_res)
    float M[16];
#pragma unroll
    for (int k = 0; k < 16; ++k)
        M[k] = expf(ar * d[8 + k] * inv_rms + b_res[k]);

    for (int it = 0; it < 20; ++it) {
#pragma unroll
        for (int i = 0; i < 4; ++i) {
            const float rs = M[i*4+0] + M[i*4+1] + M[i*4+2] + M[i*4+3] + 1e-8f;
#pragma unroll
            for (int j = 0; j < 4; ++j) M[i*4+j] = M[i*4+j] / rs;
        }
#pragma unroll
        for (int j = 0; j < 4; ++j) {
            const float cs = M[0*4+j] + M[1*4+j] + M[2*4+j] + M[3*4+j] + 1e-8f;
#pragma unroll
            for (int i = 0; i < 4; ++i) M[i*4+j] = M[i*4+j] / cs;
        }
    }

    float* p = params + (size_t)row * 24;
#pragma unroll
    for (int j = 0; j < 4; ++j)  p[j]     = Hpre[j];
#pragma unroll
    for (int j = 0; j < 4; ++j)  p[4 + j] = Hpost[j];
#pragma unroll
    for (int k = 0; k < 16; ++k) p[8 + k] = M[k];
}

// ---------------------------------------------------------------------------
// Kernel 3: output. One block per batch row; x row held in registers
// (64 floats/thread), block-reduced RMS of x_agg, then fused epilogue.
// ---------------------------------------------------------------------------
__global__ __launch_bounds__(256, 2) void out_kernel(
    const float* __restrict__ x,
    const float* __restrict__ w,
    const float* __restrict__ params,
    float* __restrict__ out)
{
    const float4* __restrict__ x4 = reinterpret_cast<const float4*>(x);
    const float4* __restrict__ w4 = reinterpret_cast<const float4*>(w);
    float4* __restrict__ out4 = reinterpret_cast<float4*>(out);

    const int b = blockIdx.x;
    const float* __restrict__ p = params + (size_t)b * 24;

    float Hpre[4], Hpost[4], M[16];
#pragma unroll
    for (int j = 0; j < 4; ++j)  Hpre[j]  = p[j];
#pragma unroll
    for (int j = 0; j < 4; ++j)  Hpost[j] = p[4 + j];
#pragma unroll
    for (int k = 0; k < 16; ++k) M[k]     = p[8 + k];

    const int t = threadIdx.x;
    const size_t base = (size_t)b * NC4;

    float4 xv[4][4];  // [u][stream]
    float4 agg[4];
    float ssq = 0.f;

#pragma unroll
    for (int u = 0; u < 4; ++u) {
        const int c4 = u * 256 + t;
#pragma unroll
        for (int n = 0; n < 4; ++n)
            xv[u][n] = x4[base + (size_t)n * C4 + c4];

        float4 a;
        a.x = Hpre[0]*xv[u][0].x + Hpre[1]*xv[u][1].x + Hpre[2]*xv[u][2].x + Hpre[3]*xv[u][3].x;
        a.y = Hpre[0]*xv[u][0].y + Hpre[1]*xv[u][1].y + Hpre[2]*xv[u][2].y + Hpre[3]*xv[u][3].y;
        a.z = Hpre[0]*xv[u][0].z + Hpre[1]*xv[u][1].z + Hpre[2]*xv[u][2].z + Hpre[3]*xv[u][3].z;
        a.w = Hpre[0]*xv[u][0].w + Hpre[1]*xv[u][1].w + Hpre[2]*xv[u][2].w + Hpre[3]*xv[u][3].w;
        agg[u] = a;
        ssq += a.x*a.x + a.y*a.y + a.z*a.z + a.w*a.w;
    }

    // block-wide sum of ssq
#pragma unroll
    for (int off = 32; off > 0; off >>= 1)
        ssq += __shfl_xor(ssq, off, 64);
    __shared__ float red[4];
    if ((t & 63) == 0) red[t >> 6] = ssq;
    __syncthreads();
    const float total = red[0] + red[1] + red[2] + red[3];
    const float inv = rsqrtf(total * (1.f / (float)C_DIM) + 1e-5f);

#pragma unroll
    for (int u = 0; u < 4; ++u) {
        const int c4 = u * 256 + t;
        const float4 wv = w4[c4];
        float4 y;
        y.x = agg[u].x * inv * wv.x;
        y.y = agg[u].y * inv * wv.y;
        y.z = agg[u].z * inv * wv.z;
        y.w = agg[u].w * inv * wv.w;

#pragma unroll
        for (int i = 0; i < 4; ++i) {
            float4 o;
            o.x = Hpost[i]*y.x + M[i*4+0]*xv[u][0].x + M[i*4+1]*xv[u][1].x
                               + M[i*4+2]*xv[u][2].x + M[i*4+3]*xv[u][3].x;
            o.y = Hpost[i]*y.y + M[i*4+0]*xv[u][0].y + M[i*4+1]*xv[u][1].y
                               + M[i*4+2]*xv[u][2].y + M[i*4+3]*xv[u][3].y;
            o.z = Hpost[i]*y.z + M[i*4+0]*xv[u][0].z + M[i*4+1]*xv[u][1].z
                               + M[i*4+2]*xv[u][2].z + M[i*4+3]*xv[u][3].z;
            o.w = Hpost[i]*y.w + M[i*4+0]*xv[u][0].w + M[i*4+1]*xv[u][1].w
                               + M[i*4+2]*xv[u][2].w + M[i*4+3]*xv[u][3].w;
            out4[base + (size_t)i * C4 + c4] = o;
        }
    }
}

// ---------------------------------------------------------------------------
extern "C" void kernel_launch(void* const* d_in, const int* in_sizes, int n_in,
                              void* d_out, int out_size, void* d_ws, size_t ws_size,
                              hipStream_t stream) {
    const float* x        = (const float*)d_in[0];
    const float* w        = (const float*)d_in[1];
    const float* phi_pre  = (const float*)d_in[2];
    const float* phi_post = (const float*)d_in[3];
    const float* phi_res  = (const float*)d_in[4];
    const float* b_pre    = (const float*)d_in[5];
    const float* b_post   = (const float*)d_in[6];
    const float* b_res    = (const float*)d_in[7];
    const float* a_pre    = (const float*)d_in[8];
    const float* a_post   = (const float*)d_in[9];
    const float* a_res    = (const float*)d_in[10];
    float* out = (float*)d_out;

    float* dots_part = (float*)d_ws;                        // [2][4096][25]
    float* params    = dots_part + (size_t)2 * B_ROWS * 25; // [4096][24]
    float* phiws     = params + (size_t)B_ROWS * 24;        // [24][16384]

    hipLaunchKernelGGL(repack_kernel, dim3((24 * NC4 + 255) / 256), dim3(256), 0, stream,
                       (const float4*)phi_pre, (const float4*)phi_post,
                       (const float4*)phi_res, (float4*)phiws);
    hipLaunchKernelGGL(proj_kernel, dim3(B_ROWS / 4), dim3(512), 0, stream,
                       x, phiws, dots_part);
    hipLaunchKernelGGL(finalize_kernel, dim3(B_ROWS / 256), dim3(256), 0, stream,
                       dots_part, b_pre, b_post, b_res, a_pre, a_post, a_res, params);
    hipLaunchKernelGGL(out_kernel, dim3(B_ROWS), dim3(256), 0, stream,
                       x, w, params, out);
}